// Round 1
// baseline (43.930 us; speedup 1.0000x reference)
//
#include <hip/hip_runtime.h>

#define GAMMA 0.99f
#define TAU   0.95f

constexpr int SEQ   = 16;          // elements per thread
constexpr int BLK   = 256;         // threads per block
constexpr int CHUNK = BLK * SEQ;   // 4096 elements per block

// (A,B) = (A,B) ∘ (rA,rB)  — apply right operand first, then (A,B)
__device__ __forceinline__ void post_compose(float& A, float& B, float rA, float rB) {
    B = fmaf(A, rB, B);
    A *= rA;
}
// (A,B) = (lA,lB) ∘ (A,B)  — apply (A,B) first, then left operand
__device__ __forceinline__ void pre_compose(float& A, float& B, float lA, float lB) {
    B = fmaf(lA, B, lB);
    A *= lA;
}

// ---------------- Kernel 1: per-block affine summaries ----------------
__global__ __launch_bounds__(BLK) void k_summary(
    const float* __restrict__ r, const float* __restrict__ v,
    const float* __restrict__ nv, const int* __restrict__ m,
    float4* __restrict__ blk_sum, int T)
{
    const int  tid  = threadIdx.x;
    const int  lane = tid & 63;
    const int  w    = tid >> 6;
    const long base = (long)blockIdx.x * CHUNK + (long)tid * SEQ;

    float Aa = 1.f, Ba = 0.f, Ar = 1.f, Br = 0.f;

    if (base + SEQ <= (long)T) {
        float rr[SEQ], vv[SEQ + 1], nn[SEQ], fm[SEQ];
        #pragma unroll
        for (int q = 0; q < SEQ / 4; ++q) {
            float4 t0 = ((const float4*)(r  + base))[q];
            rr[4*q+0]=t0.x; rr[4*q+1]=t0.y; rr[4*q+2]=t0.z; rr[4*q+3]=t0.w;
            float4 t1 = ((const float4*)(v  + base))[q];
            vv[4*q+0]=t1.x; vv[4*q+1]=t1.y; vv[4*q+2]=t1.z; vv[4*q+3]=t1.w;
            float4 t2 = ((const float4*)(nv + base))[q];
            nn[4*q+0]=t2.x; nn[4*q+1]=t2.y; nn[4*q+2]=t2.z; nn[4*q+3]=t2.w;
            int4   t3 = ((const int4*)(m   + base))[q];
            fm[4*q+0]=(float)t3.x; fm[4*q+1]=(float)t3.y;
            fm[4*q+2]=(float)t3.z; fm[4*q+3]=(float)t3.w;
        }
        vv[SEQ] = (base + SEQ < (long)T) ? v[base + SEQ] : 0.f;
        #pragma unroll
        for (int i = SEQ - 1; i >= 0; --i) {
            float a = GAMMA * TAU * fm[i];
            float b = rr[i] + GAMMA * fm[i] * vv[i+1] - vv[i];
            float c = GAMMA * fm[i];
            float d = rr[i] + GAMMA * (1.f - fm[i]) * nn[i];
            pre_compose(Aa, Ba, a, b);
            pre_compose(Ar, Br, c, d);
        }
    } else if (base < (long)T) {
        // tail (never taken for T = 2^22, kept for generality; unrolled, const idx)
        #pragma unroll
        for (int ii = 0; ii < SEQ; ++ii) {
            int i = SEQ - 1 - ii;
            long idx = base + i;
            bool val = idx < (long)T;
            float rr  = val ? r[idx]  : 0.f;
            float vv0 = val ? v[idx]  : 0.f;
            float vv1 = (idx + 1 < (long)T) ? v[idx + 1] : 0.f;
            float nn  = val ? nv[idx] : 0.f;
            float fm  = val ? (float)m[idx] : 0.f;
            float a = val ? GAMMA * TAU * fm : 1.f;
            float b = val ? (rr + GAMMA * fm * vv1 - vv0) : 0.f;
            float c = val ? GAMMA * fm : 1.f;
            float d = val ? (rr + GAMMA * (1.f - fm) * nn) : 0.f;
            pre_compose(Aa, Ba, a, b);
            pre_compose(Ar, Br, c, d);
        }
    }

    // wave-level suffix scan (stride doubling keeps segments contiguous)
    #pragma unroll
    for (int st = 1; st < 64; st <<= 1) {
        float oAa = __shfl_down(Aa, st);
        float oBa = __shfl_down(Ba, st);
        float oAr = __shfl_down(Ar, st);
        float oBr = __shfl_down(Br, st);
        if (lane + st < 64) {
            post_compose(Aa, Ba, oAa, oBa);
            post_compose(Ar, Br, oAr, oBr);
        }
    }

    __shared__ float wSum[4][4];
    if (lane == 0) { wSum[w][0]=Aa; wSum[w][1]=Ba; wSum[w][2]=Ar; wSum[w][3]=Br; }
    __syncthreads();
    if (tid == 0) {
        float SAa=1.f, SBa=0.f, SAr=1.f, SBr=0.f;
        for (int j = 3; j >= 0; --j) {
            pre_compose(SAa, SBa, wSum[j][0], wSum[j][1]);
            pre_compose(SAr, SBr, wSum[j][2], wSum[j][3]);
        }
        blk_sum[blockIdx.x] = make_float4(SAa, SBa, SAr, SBr);
    }
}

// ---------------- Kernel 2: suffix scan of 1024 block maps ----------------
__global__ __launch_bounds__(1024) void k_scan(
    const float4* __restrict__ blk_sum, float2* __restrict__ carry, int n)
{
    __shared__ float sAa[1024], sBa[1024], sAr[1024], sBr[1024];
    const int t = threadIdx.x;
    float Aa=1.f, Ba=0.f, Ar=1.f, Br=0.f;
    if (t < n) { float4 s = blk_sum[t]; Aa=s.x; Ba=s.y; Ar=s.z; Br=s.w; }
    sAa[t]=Aa; sBa[t]=Ba; sAr[t]=Ar; sBr[t]=Br;
    __syncthreads();
    for (int st = 1; st < 1024; st <<= 1) {
        float oAa=1.f, oBa=0.f, oAr=1.f, oBr=0.f;
        if (t + st < 1024) { oAa=sAa[t+st]; oBa=sBa[t+st]; oAr=sAr[t+st]; oBr=sBr[t+st]; }
        __syncthreads();
        post_compose(Aa, Ba, oAa, oBa);
        post_compose(Ar, Br, oAr, oBr);
        sAa[t]=Aa; sBa[t]=Ba; sAr[t]=Ar; sBr[t]=Br;
        __syncthreads();
    }
    if (t < n) {
        float ca = (t + 1 < n) ? sBa[t+1] : 0.f;
        float cr = (t + 1 < n) ? sBr[t+1] : 0.f;
        carry[t] = make_float2(ca, cr);
    }
}

// ---------------- Kernel 3: replay with carries, write outputs ----------------
__global__ __launch_bounds__(BLK) void k_final(
    const float* __restrict__ r, const float* __restrict__ v,
    const float* __restrict__ nv, const int* __restrict__ m,
    const float2* __restrict__ carry,
    float* __restrict__ out_adv, float* __restrict__ out_ret, int T)
{
    const int  tid  = threadIdx.x;
    const int  lane = tid & 63;
    const int  w    = tid >> 6;
    const long base = (long)blockIdx.x * CHUNK + (long)tid * SEQ;

    float delta[SEQ], dd[SEQ], fm[SEQ];
    unsigned vbits = 0;
    float Aa = 1.f, Ba = 0.f, Ar = 1.f, Br = 0.f;
    const bool full = (base + SEQ <= (long)T);

    if (full) {
        vbits = 0xFFFFu;
        float rr[SEQ], vv[SEQ + 1], nn[SEQ];
        #pragma unroll
        for (int q = 0; q < SEQ / 4; ++q) {
            float4 t0 = ((const float4*)(r  + base))[q];
            rr[4*q+0]=t0.x; rr[4*q+1]=t0.y; rr[4*q+2]=t0.z; rr[4*q+3]=t0.w;
            float4 t1 = ((const float4*)(v  + base))[q];
            vv[4*q+0]=t1.x; vv[4*q+1]=t1.y; vv[4*q+2]=t1.z; vv[4*q+3]=t1.w;
            float4 t2 = ((const float4*)(nv + base))[q];
            nn[4*q+0]=t2.x; nn[4*q+1]=t2.y; nn[4*q+2]=t2.z; nn[4*q+3]=t2.w;
            int4   t3 = ((const int4*)(m   + base))[q];
            fm[4*q+0]=(float)t3.x; fm[4*q+1]=(float)t3.y;
            fm[4*q+2]=(float)t3.z; fm[4*q+3]=(float)t3.w;
        }
        vv[SEQ] = (base + SEQ < (long)T) ? v[base + SEQ] : 0.f;
        #pragma unroll
        for (int i = SEQ - 1; i >= 0; --i) {
            delta[i] = rr[i] + GAMMA * fm[i] * vv[i+1] - vv[i];
            dd[i]    = rr[i] + GAMMA * (1.f - fm[i]) * nn[i];
            pre_compose(Aa, Ba, GAMMA * TAU * fm[i], delta[i]);
            pre_compose(Ar, Br, GAMMA * fm[i], dd[i]);
        }
    } else {
        #pragma unroll
        for (int ii = 0; ii < SEQ; ++ii) {
            int i = SEQ - 1 - ii;
            long idx = base + i;
            bool val = idx < (long)T;
            float rr  = val ? r[idx]  : 0.f;
            float vv0 = val ? v[idx]  : 0.f;
            float vv1 = (idx + 1 < (long)T) ? v[idx + 1] : 0.f;
            float nn  = val ? nv[idx] : 0.f;
            fm[i] = val ? (float)m[idx] : 0.f;
            if (val) vbits |= (1u << i);
            delta[i] = val ? (rr + GAMMA * fm[i] * vv1 - vv0) : 0.f;
            dd[i]    = val ? (rr + GAMMA * (1.f - fm[i]) * nn) : 0.f;
            pre_compose(Aa, Ba, val ? GAMMA * TAU * fm[i] : 1.f, delta[i]);
            pre_compose(Ar, Br, val ? GAMMA * fm[i] : 1.f, dd[i]);
        }
    }

    // wave-level inclusive suffix scan
    #pragma unroll
    for (int st = 1; st < 64; st <<= 1) {
        float oAa = __shfl_down(Aa, st);
        float oBa = __shfl_down(Ba, st);
        float oAr = __shfl_down(Ar, st);
        float oBr = __shfl_down(Br, st);
        if (lane + st < 64) {
            post_compose(Aa, Ba, oAa, oBa);
            post_compose(Ar, Br, oAr, oBr);
        }
    }
    // thread-exclusive (within wave) = neighbor lane's inclusive
    float eAa = __shfl_down(Aa, 1);
    float eBa = __shfl_down(Ba, 1);
    float eAr = __shfl_down(Ar, 1);
    float eBr = __shfl_down(Br, 1);
    if (lane == 63) { eAa=1.f; eBa=0.f; eAr=1.f; eBr=0.f; }

    __shared__ float wSum[4][4];
    if (lane == 0) { wSum[w][0]=Aa; wSum[w][1]=Ba; wSum[w][2]=Ar; wSum[w][3]=Br; }
    __syncthreads();

    // wave-exclusive map: waves w+1..3
    float WAa=1.f, WBa=0.f, WAr=1.f, WBr=0.f;
    for (int j = 3; j > w; --j) {
        pre_compose(WAa, WBa, wSum[j][0], wSum[j][1]);
        pre_compose(WAr, WBr, wSum[j][2], wSum[j][3]);
    }

    float2 cb = carry[blockIdx.x];
    float xa = fmaf(WAa, cb.x, WBa);   // value at this wave's right edge
    float xr = fmaf(WAr, cb.y, WBr);
    xa = fmaf(eAa, xa, eBa);           // value at this thread's right edge
    xr = fmaf(eAr, xr, eBr);

    // serial replay of 16 elements (right to left)
    float ra[SEQ], rt[SEQ];
    #pragma unroll
    for (int i = SEQ - 1; i >= 0; --i) {
        bool val = (vbits >> i) & 1u;
        float a = val ? GAMMA * TAU * fm[i] : 1.f;
        float c = val ? GAMMA * fm[i]       : 1.f;
        xa = fmaf(a, xa, delta[i]);
        xr = fmaf(c, xr, dd[i]);
        ra[i] = xa; rt[i] = xr;
    }

    if (full) {
        #pragma unroll
        for (int q = 0; q < SEQ / 4; ++q) {
            ((float4*)(out_adv + base))[q] =
                make_float4(ra[4*q], ra[4*q+1], ra[4*q+2], ra[4*q+3]);
            ((float4*)(out_ret + base))[q] =
                make_float4(rt[4*q], rt[4*q+1], rt[4*q+2], rt[4*q+3]);
        }
    } else {
        #pragma unroll
        for (int i = 0; i < SEQ; ++i) {
            if (base + i < (long)T) {
                out_adv[base + i] = ra[i];
                out_ret[base + i] = rt[i];
            }
        }
    }
}

extern "C" void kernel_launch(void* const* d_in, const int* in_sizes, int n_in,
                              void* d_out, int out_size, void* d_ws, size_t ws_size,
                              hipStream_t stream) {
    const float* r  = (const float*)d_in[0];
    const float* v  = (const float*)d_in[1];
    const float* nv = (const float*)d_in[2];
    const int*   m  = (const int*)d_in[3];
    const int T = in_sizes[0];
    const int nblk = (T + CHUNK - 1) / CHUNK;   // 1024 for T = 4'194'304

    float4* blk_sum = (float4*)d_ws;
    float2* carry   = (float2*)((char*)d_ws + (size_t)nblk * sizeof(float4));

    float* out_adv = (float*)d_out;
    float* out_ret = (float*)d_out + T;

    k_summary<<<nblk, BLK, 0, stream>>>(r, v, nv, m, blk_sum, T);
    k_scan<<<1, 1024, 0, stream>>>(blk_sum, carry, nblk);
    k_final<<<nblk, BLK, 0, stream>>>(r, v, nv, m, carry, out_adv, out_ret, T);
}